// Round 1
// baseline (683.126 us; speedup 1.0000x reference)
//
#include <hip/hip_runtime.h>
#include <hip/hip_bf16.h>
#include <math.h>

#define NN   20000
#define EE   160000
#define NBAT 64
#define NF   128
#define NH   64
#define NHEAD 16
#define NCLS 10
#define ETOT (EE + NN)   // edges + self loops = 180000

// ---------------------------------------------------------------- CSR build
__global__ void k_init_deg(int* __restrict__ deg) {
    int n = blockIdx.x * 256 + threadIdx.x;
    if (n < NN) deg[n] = 1;                 // self-loop
}

__global__ void k_hist(const int* __restrict__ ei, int* __restrict__ deg) {
    int e = blockIdx.x * 256 + threadIdx.x;
    if (e < EE) atomicAdd(&deg[ei[EE + e]], 1);   // dst row
}

// single block, 1024 threads: exclusive scan of deg[NN] -> rowptr, cursor
__global__ void k_scan(const int* __restrict__ deg, int* __restrict__ rowptr,
                       int* __restrict__ cursor) {
    const int T = 1024, PER = (NN + T - 1) / T;   // 20
    __shared__ int part[T];
    int t = threadIdx.x;
    int local[PER];
    int s = 0;
    #pragma unroll
    for (int i = 0; i < PER; ++i) {
        int idx = t * PER + i;
        int v = (idx < NN) ? deg[idx] : 0;
        local[i] = v; s += v;
    }
    part[t] = s;
    __syncthreads();
    for (int off = 1; off < T; off <<= 1) {
        int v = (t >= off) ? part[t - off] : 0;
        __syncthreads();
        part[t] += v;
        __syncthreads();
    }
    int ex = (t == 0) ? 0 : part[t - 1];
    #pragma unroll
    for (int i = 0; i < PER; ++i) {
        int idx = t * PER + i;
        if (idx < NN) { rowptr[idx] = ex; cursor[idx] = ex; ex += local[i]; }
    }
    if (t == T - 1) rowptr[NN] = ex;
}

__global__ void k_scatter(const int* __restrict__ ei, int* __restrict__ cursor,
                          int* __restrict__ csr) {
    int e = blockIdx.x * 256 + threadIdx.x;
    if (e >= ETOT) return;
    int s, d;
    if (e < EE) { s = ei[e]; d = ei[EE + e]; }
    else        { s = e - EE; d = s; }
    int pos = atomicAdd(&cursor[d], 1);
    csr[pos] = s;
}

__global__ void k_bounds(const int* __restrict__ batch, int* __restrict__ bstart) {
    int n = blockIdx.x * 256 + threadIdx.x;
    if (n >= NN) return;
    int b = batch[n];
    if (n == 0) for (int bb = 0; bb <= b; ++bb) bstart[bb] = 0;
    int bn = (n + 1 < NN) ? batch[n + 1] : NBAT;
    for (int bb = b + 1; bb <= bn; ++bb) bstart[bb] = n + 1;
}

// ---------------------------------------------------------------- GEMM + bias
// O[M][1024] = A[M][K] @ W[K][1024] + b   (two problems via blockIdx.z)
template<int K>
__global__ __launch_bounds__(256) void k_gemm(
    const float* __restrict__ A, int M,
    const float* __restrict__ W0, const float* __restrict__ b0, float* __restrict__ O0,
    const float* __restrict__ W1, const float* __restrict__ b1, float* __restrict__ O1)
{
    const float* W  = blockIdx.z ? W1 : W0;
    const float* bi = blockIdx.z ? b1 : b0;
    float*       O  = blockIdx.z ? O1 : O0;
    const int r0 = blockIdx.x * 64;
    const int c0 = blockIdx.y * 64;
    __shared__ __align__(16) float As[64][64];  // [k][r], r index XOR-swizzled
    __shared__ __align__(16) float Ws[64][64];  // [k][c]
    const int tid = threadIdx.x;
    const int tx = tid & 15, ty = tid >> 4;
    float acc[4][4] = {};

    for (int kt = 0; kt < K; kt += 64) {
        #pragma unroll
        for (int it = 0; it < 4; ++it) {
            int r  = (tid >> 4) + it * 16;      // 0..63
            int k4 = (tid & 15) * 4;            // 0..60
            int gr = r0 + r;
            float4 v = make_float4(0.f, 0.f, 0.f, 0.f);
            if (gr < M) v = *(const float4*)(A + (size_t)gr * K + kt + k4);
            As[k4 + 0][r ^ (((k4 + 0) & 7) << 2)] = v.x;
            As[k4 + 1][r ^ (((k4 + 1) & 7) << 2)] = v.y;
            As[k4 + 2][r ^ (((k4 + 2) & 7) << 2)] = v.z;
            As[k4 + 3][r ^ (((k4 + 3) & 7) << 2)] = v.w;
        }
        #pragma unroll
        for (int it = 0; it < 4; ++it) {
            int kk = (tid >> 4) + it * 16;
            int c4 = (tid & 15) * 4;
            *(float4*)&Ws[kk][c4] =
                *(const float4*)(W + (size_t)(kt + kk) * 1024 + c0 + c4);
        }
        __syncthreads();
        #pragma unroll 16
        for (int kk = 0; kk < 64; ++kk) {
            const float4 a4 = *(const float4*)&As[kk][(ty * 4) ^ ((kk & 7) << 2)];
            const float4 w4 = *(const float4*)&Ws[kk][tx * 4];
            const float aa[4] = {a4.x, a4.y, a4.z, a4.w};
            const float ww[4] = {w4.x, w4.y, w4.z, w4.w};
            #pragma unroll
            for (int i = 0; i < 4; ++i)
                #pragma unroll
                for (int j = 0; j < 4; ++j)
                    acc[i][j] = fmaf(aa[i], ww[j], acc[i][j]);
        }
        __syncthreads();
    }

    const float4 bv = *(const float4*)(bi + c0 + tx * 4);
    #pragma unroll
    for (int i = 0; i < 4; ++i) {
        int gr = r0 + ty * 4 + i;
        if (gr < M) {
            float4 o;
            o.x = acc[i][0] + bv.x; o.y = acc[i][1] + bv.y;
            o.z = acc[i][2] + bv.z; o.w = acc[i][3] + bv.w;
            *(float4*)(O + (size_t)gr * 1024 + c0 + tx * 4) = o;
        }
    }
}

// ------------------------------------------------- attention + aggregation
// one wave per node; lane = (head h = lane>>2, c-chunk cc = lane&3, 16 c each)
__global__ __launch_bounds__(256) void k_attn(
    const float* __restrict__ xl, const float* __restrict__ xr,
    const float* __restrict__ att, const float* __restrict__ bias,
    const int* __restrict__ rowptr, const int* __restrict__ csr,
    float* __restrict__ hout)
{
    const int wave = threadIdx.x >> 6;
    const int lane = threadIdx.x & 63;
    const int n = blockIdx.x * 4 + wave;
    if (n >= NN) return;
    const int h  = lane >> 2;
    const int cc = lane & 3;
    const int cb = h * NH + cc * 16;          // col base within [16*64]

    float attv[16], xrv[16], acc[16];
    #pragma unroll
    for (int i = 0; i < 4; ++i)
        *(float4*)(attv + i * 4) = *(const float4*)(att + cb + i * 4);
    const float* xrp = xr + (size_t)n * 1024 + cb;
    #pragma unroll
    for (int i = 0; i < 4; ++i)
        *(float4*)(xrv + i * 4) = *(const float4*)(xrp + i * 4);
    #pragma unroll
    for (int j = 0; j < 16; ++j) acc[j] = 0.f;

    float m = -INFINITY, den = 0.f;
    const int e0 = rowptr[n], e1 = rowptr[n + 1];
    for (int e = e0; e < e1; ++e) {
        const int s = csr[e];
        const float* xlp = xl + (size_t)s * 1024 + cb;
        float xlv[16];
        #pragma unroll
        for (int i = 0; i < 4; ++i)
            *(float4*)(xlv + i * 4) = *(const float4*)(xlp + i * 4);
        float partial = 0.f;
        #pragma unroll
        for (int j = 0; j < 16; ++j) {
            float t = xlv[j] + xrv[j];
            t = fmaxf(t, 0.2f * t);                      // LeakyReLU(0.2)
            partial = fmaf(t, attv[j], partial);
        }
        partial += __shfl_xor(partial, 1);
        partial += __shfl_xor(partial, 2);               // logit, replicated x4
        const float nm = fmaxf(m, partial);
        const float p  = __expf(partial - nm);
        const float sc = __expf(m - nm);                 // exp(-inf)=0 first iter
        den = den * sc + p;
        #pragma unroll
        for (int j = 0; j < 16; ++j)
            acc[j] = fmaf(acc[j], sc, p * xlv[j]);
        m = nm;
    }

    const float inv = 1.f / den;
    float v[16];
    #pragma unroll
    for (int j = 0; j < 16; ++j) v[j] = acc[j] * inv;
    #pragma unroll
    for (int mask = 4; mask <= 32; mask <<= 1)
        #pragma unroll
        for (int j = 0; j < 16; ++j) v[j] += __shfl_xor(v[j], mask);

    if (h == 0) {                                        // lanes 0..3 hold head-sums
        float bvv[16];
        #pragma unroll
        for (int i = 0; i < 4; ++i)
            *(float4*)(bvv + i * 4) = *(const float4*)(bias + cc * 16 + i * 4);
        float* hp = hout + (size_t)n * NH + cc * 16;
        #pragma unroll
        for (int i = 0; i < 4; ++i) {
            float4 o;
            float t;
            t = v[i*4+0] * 0.0625f + bvv[i*4+0]; o.x = fmaxf(t, 0.01f * t);
            t = v[i*4+1] * 0.0625f + bvv[i*4+1]; o.y = fmaxf(t, 0.01f * t);
            t = v[i*4+2] * 0.0625f + bvv[i*4+2]; o.z = fmaxf(t, 0.01f * t);
            t = v[i*4+3] * 0.0625f + bvv[i*4+3]; o.w = fmaxf(t, 0.01f * t);
            *(float4*)(hp + i * 4) = o;
        }
    }
}

// ---------------------------------------------------------------- pool + heads
__global__ void k_pool(const float* __restrict__ h2, const int* __restrict__ bstart,
                       const float* __restrict__ Wc, const float* __restrict__ bc,
                       const float* __restrict__ Wv, const float* __restrict__ bv,
                       float* __restrict__ out)
{
    const int b = blockIdx.x, c = threadIdx.x;   // 64 threads
    const int s = bstart[b], e = bstart[b + 1];
    float sum = 0.f;
    for (int n = s; n < e; ++n) sum += h2[(size_t)n * NH + c];
    const float cnt = (float)(e - s);
    const float pooled = sum / fmaxf(cnt, 1.f);
    __shared__ float pl[NH];
    pl[c] = pooled;
    __syncthreads();
    if (c < NCLS) {
        float a = bc[c];
        for (int k = 0; k < NH; ++k) a = fmaf(pl[k], Wc[k * NCLS + c], a);
        out[b * NCLS + c] = a;
    } else if (c == NCLS) {
        float a = bv[0];
        for (int k = 0; k < NH; ++k) a = fmaf(pl[k], Wv[k], a);
        out[NBAT * NCLS + b] = a;
    }
}

// ---------------------------------------------------------------- launch
extern "C" void kernel_launch(void* const* d_in, const int* in_sizes, int n_in,
                              void* d_out, int out_size, void* d_ws, size_t ws_size,
                              hipStream_t stream)
{
    const float* x     = (const float*)d_in[0];
    const int*   ei    = (const int*)  d_in[1];
    const int*   batch = (const int*)  d_in[2];
    const float* W1l = (const float*)d_in[3],  *b1l = (const float*)d_in[4];
    const float* W1r = (const float*)d_in[5],  *b1r = (const float*)d_in[6];
    const float* att1 = (const float*)d_in[7], *bias1 = (const float*)d_in[8];
    const float* W2l = (const float*)d_in[9],  *b2l = (const float*)d_in[10];
    const float* W2r = (const float*)d_in[11], *b2r = (const float*)d_in[12];
    const float* att2 = (const float*)d_in[13], *bias2 = (const float*)d_in[14];
    const float* Wc = (const float*)d_in[15],  *bc = (const float*)d_in[16];
    const float* Wv = (const float*)d_in[17],  *bv = (const float*)d_in[18];
    float* out = (float*)d_out;

    char* ws = (char*)d_ws;
    size_t off = 0;
    auto carve = [&](size_t bytes) {
        char* p = ws + off;
        off = (off + bytes + 255) & ~(size_t)255;
        return p;
    };
    float* xl     = (float*)carve((size_t)NN * 1024 * 4);
    float* xr     = (float*)carve((size_t)NN * 1024 * 4);
    float* h1     = (float*)carve((size_t)NN * NH * 4);
    float* h2     = (float*)carve((size_t)NN * NH * 4);
    int*   deg    = (int*)carve((size_t)NN * 4);
    int*   cursor = (int*)carve((size_t)NN * 4);
    int*   rowptr = (int*)carve((size_t)(NN + 1) * 4);
    int*   csr    = (int*)carve((size_t)ETOT * 4);
    int*   bstart = (int*)carve((size_t)(NBAT + 1) * 4);

    // graph preprocessing (same every call; inputs are re-restored each launch)
    k_init_deg<<<(NN + 255) / 256, 256, 0, stream>>>(deg);
    k_hist   <<<(EE + 255) / 256, 256, 0, stream>>>(ei, deg);
    k_scan   <<<1, 1024, 0, stream>>>(deg, rowptr, cursor);
    k_scatter<<<(ETOT + 255) / 256, 256, 0, stream>>>(ei, cursor, csr);
    k_bounds <<<(NN + 255) / 256, 256, 0, stream>>>(batch, bstart);

    const int MB = (NN + 63) / 64;   // 313 row blocks
    // layer 1
    k_gemm<NF><<<dim3(MB, 16, 2), 256, 0, stream>>>(x, NN, W1l, b1l, xl, W1r, b1r, xr);
    k_attn<<<NN / 4, 256, 0, stream>>>(xl, xr, att1, bias1, rowptr, csr, h1);
    // layer 2
    k_gemm<NH><<<dim3(MB, 16, 2), 256, 0, stream>>>(h1, NN, W2l, b2l, xl, W2r, b2r, xr);
    k_attn<<<NN / 4, 256, 0, stream>>>(xl, xr, att2, bias2, rowptr, csr, h2);
    // pool + heads
    k_pool<<<NBAT, NH, 0, stream>>>(h2, bstart, Wc, bc, Wv, bv, out);
}

// Round 3
// 562.110 us; speedup vs baseline: 1.2153x; 1.2153x over previous
//
#include <hip/hip_runtime.h>
#include <hip/hip_bf16.h>
#include <math.h>

#define NN   20000
#define EE   160000
#define NBAT 64
#define NF   128
#define NH   64
#define NHEAD 16
#define NCLS 10
#define ETOT (EE + NN)   // edges + self loops = 180000

typedef __attribute__((ext_vector_type(8))) short short8;
typedef __attribute__((ext_vector_type(4))) float f32x4;
typedef unsigned short ushort_t;

// bf16 helpers (bit-level, RNE; no NaN in our data)
static __device__ __forceinline__ ushort_t f2bf_rn(float x) {
    unsigned u = __builtin_bit_cast(unsigned, x);
    unsigned r = (u + 0x7fffu + ((u >> 16) & 1u)) >> 16;
    return (ushort_t)r;
}
static __device__ __forceinline__ float bf2f(ushort_t u) {
    unsigned v = (unsigned)u << 16;
    return __builtin_bit_cast(float, v);
}

// ---------------------------------------------------------------- CSR build
__global__ void k_init_deg(int* __restrict__ deg) {
    int n = blockIdx.x * 256 + threadIdx.x;
    if (n < NN) deg[n] = 1;                 // self-loop
}

__global__ void k_hist(const int* __restrict__ ei, int* __restrict__ deg) {
    int e = blockIdx.x * 256 + threadIdx.x;
    if (e < EE) atomicAdd(&deg[ei[EE + e]], 1);   // dst row
}

__global__ void k_scan(const int* __restrict__ deg, int* __restrict__ rowptr,
                       int* __restrict__ cursor) {
    const int T = 1024, PER = (NN + T - 1) / T;   // 20
    __shared__ int part[T];
    int t = threadIdx.x;
    int local[PER];
    int s = 0;
    #pragma unroll
    for (int i = 0; i < PER; ++i) {
        int idx = t * PER + i;
        int v = (idx < NN) ? deg[idx] : 0;
        local[i] = v; s += v;
    }
    part[t] = s;
    __syncthreads();
    for (int off = 1; off < T; off <<= 1) {
        int v = (t >= off) ? part[t - off] : 0;
        __syncthreads();
        part[t] += v;
        __syncthreads();
    }
    int ex = (t == 0) ? 0 : part[t - 1];
    #pragma unroll
    for (int i = 0; i < PER; ++i) {
        int idx = t * PER + i;
        if (idx < NN) { rowptr[idx] = ex; cursor[idx] = ex; ex += local[i]; }
    }
    if (t == T - 1) rowptr[NN] = ex;
}

__global__ void k_scatter(const int* __restrict__ ei, int* __restrict__ cursor,
                          int* __restrict__ csr) {
    int e = blockIdx.x * 256 + threadIdx.x;
    if (e >= ETOT) return;
    int s, d;
    if (e < EE) { s = ei[e]; d = ei[EE + e]; }
    else        { s = e - EE; d = s; }
    int pos = atomicAdd(&cursor[d], 1);
    csr[pos] = s;
}

__global__ void k_bounds(const int* __restrict__ batch, int* __restrict__ bstart) {
    int n = blockIdx.x * 256 + threadIdx.x;
    if (n >= NN) return;
    int b = batch[n];
    if (n == 0) for (int bb = 0; bb <= b; ++bb) bstart[bb] = 0;
    int bn = (n + 1 < NN) ? batch[n + 1] : NBAT;
    for (int bb = b + 1; bb <= bn; ++bb) bstart[bb] = n + 1;
}

// ---------------------------------------------------------------- splits
// A [count] fp32 -> hi/lo bf16 (same layout), vectorized x4
__global__ void k_split_a(const float* __restrict__ A, ushort_t* __restrict__ hi,
                          ushort_t* __restrict__ lo, int count4) {
    int idx = blockIdx.x * 256 + threadIdx.x;
    if (idx >= count4) return;
    float4 x = *(const float4*)(A + idx * 4);
    ushort4 h, l;
    h.x = f2bf_rn(x.x); l.x = f2bf_rn(x.x - bf2f(h.x));
    h.y = f2bf_rn(x.y); l.y = f2bf_rn(x.y - bf2f(h.y));
    h.z = f2bf_rn(x.z); l.z = f2bf_rn(x.z - bf2f(h.z));
    h.w = f2bf_rn(x.w); l.w = f2bf_rn(x.w - bf2f(h.w));
    *(ushort4*)(hi + idx * 4) = h;
    *(ushort4*)(lo + idx * 4) = l;
}

// W [K][1024] fp32 -> Wt hi/lo [1024][K] bf16 (transposed)
template<int K>
__global__ void k_split_w(const float* __restrict__ W, ushort_t* __restrict__ hi,
                          ushort_t* __restrict__ lo) {
    int idx = blockIdx.x * 256 + threadIdx.x;
    if (idx >= K * 1024) return;
    int k = idx >> 10, n = idx & 1023;
    float x = W[idx];
    ushort_t h = f2bf_rn(x);
    hi[n * K + k] = h;
    lo[n * K + k] = f2bf_rn(x - bf2f(h));
}

// ------------------------------------------------- split-bf16 MFMA GEMM
// O[M][1024] = split(A)[M][K] @ split(W)[K][1024] + b  (3-term: hh + hl + lh)
// Wt layouts are transposed: [1024][K]. blockIdx.z selects weight set.
template<int K>
__global__ __launch_bounds__(256) void k_gemm_mfma(
    const ushort_t* __restrict__ Ahi, const ushort_t* __restrict__ Alo, int M,
    const ushort_t* __restrict__ W0hi, const ushort_t* __restrict__ W0lo,
    const float* __restrict__ b0, float* __restrict__ O0,
    const ushort_t* __restrict__ W1hi, const ushort_t* __restrict__ W1lo,
    const float* __restrict__ b1, float* __restrict__ O1)
{
    const ushort_t* Whi = blockIdx.z ? W1hi : W0hi;
    const ushort_t* Wlo = blockIdx.z ? W1lo : W0lo;
    const float*    bi  = blockIdx.z ? b1 : b0;
    float*          O   = blockIdx.z ? O1 : O0;

    const int r0 = blockIdx.x * 128;
    const int c0 = blockIdx.y * 128;

    __shared__ __align__(16) ushort_t As_hi[128 * 64];
    __shared__ __align__(16) ushort_t As_lo[128 * 64];
    __shared__ __align__(16) ushort_t Ws_hi[128 * 64];
    __shared__ __align__(16) ushort_t Ws_lo[128 * 64];

    const int t = threadIdx.x;
    const int lane = t & 63;
    const int wv = t >> 6, wr = wv >> 1, wc = wv & 1;
    const int fr = lane & 15;            // fragment row/col
    const int k0 = (lane >> 4) * 8;      // k-slice within 32

    f32x4 acc[4][4] = {};

    for (int kt = 0; kt < K; kt += 64) {
        // ---- stage (reg -> LDS, XOR-swizzled writes) ----
        #pragma unroll
        for (int p = 0; p < 4; ++p) {
            int idx = p * 256 + t;       // 0..1023
            int m  = idx >> 3;           // 0..127
            int kc = (idx & 7) * 8;      // 0..56
            int gr = r0 + m;
            uint4 vh = make_uint4(0, 0, 0, 0), vl = make_uint4(0, 0, 0, 0);
            if (gr < M) {
                vh = *(const uint4*)(Ahi + (size_t)gr * K + kt + kc);
                vl = *(const uint4*)(Alo + (size_t)gr * K + kt + kc);
            }
            int sw = (m * 128 + kc * 2) ^ ((m & 7) << 4);
            *(uint4*)((char*)As_hi + sw) = vh;
            *(uint4*)((char*)As_lo + sw) = vl;
            uint4 wh = *(const uint4*)(Whi + (size_t)(c0 + m) * K + kt + kc);
            uint4 wl = *(const uint4*)(Wlo + (size_t)(c0 + m) * K + kt + kc);
            *(uint4*)((char*)Ws_hi + sw) = wh;
            *(uint4*)((char*)Ws_lo + sw) = wl;
        }
        __syncthreads();

        // ---- MFMA ----
        #pragma unroll
        for (int ks = 0; ks < 64; ks += 32) {
            short8 ah[4], al[4], bh[4], bl[4];
            #pragma unroll
            for (int i = 0; i < 4; ++i) {
                int row = wr * 64 + i * 16 + fr;
                int off = (row * 128 + (ks + k0) * 2) ^ ((row & 7) << 4);
                ah[i] = *(const short8*)((const char*)As_hi + off);
                al[i] = *(const short8*)((const char*)As_lo + off);
            }
            #pragma unroll
            for (int j = 0; j < 4; ++j) {
                int col = wc * 64 + j * 16 + fr;
                int off = (col * 128 + (ks + k0) * 2) ^ ((col & 7) << 4);
                bh[j] = *(const short8*)((const char*)Ws_hi + off);
                bl[j] = *(const short8*)((const char*)Ws_lo + off);
            }
            #pragma unroll
            for (int i = 0; i < 4; ++i)
                #pragma unroll
                for (int j = 0; j < 4; ++j) {
                    acc[i][j] = __builtin_amdgcn_mfma_f32_16x16x32_bf16(ah[i], bh[j], acc[i][j], 0, 0, 0);
                    acc[i][j] = __builtin_amdgcn_mfma_f32_16x16x32_bf16(ah[i], bl[j], acc[i][j], 0, 0, 0);
                    acc[i][j] = __builtin_amdgcn_mfma_f32_16x16x32_bf16(al[i], bh[j], acc[i][j], 0, 0, 0);
                }
        }
        __syncthreads();
    }

    // ---- epilogue: + bias, store ----
    float bj[4];
    #pragma unroll
    for (int j = 0; j < 4; ++j) bj[j] = bi[c0 + wc * 64 + j * 16 + fr];
    #pragma unroll
    for (int i = 0; i < 4; ++i) {
        int rbase = r0 + wr * 64 + i * 16 + (lane >> 4) * 4;
        #pragma unroll
        for (int r = 0; r < 4; ++r) {
            int gr = rbase + r;
            if (gr < M) {
                #pragma unroll
                for (int j = 0; j < 4; ++j)
                    O[(size_t)gr * 1024 + c0 + wc * 64 + j * 16 + fr] = acc[i][j][r] + bj[j];
            }
        }
    }
}

// ------------------------------------------------- attention + aggregation
// one wave per node; lane = (head h = lane>>2, c-chunk cc = lane&3, 16 c each)
// SPLIT=1: write bf16 hi/lo (layer-1 output feeding gemm2); SPLIT=0: write fp32
template<int SPLIT>
__global__ __launch_bounds__(256) void k_attn(
    const float* __restrict__ xl, const float* __restrict__ xr,
    const float* __restrict__ att, const float* __restrict__ bias,
    const int* __restrict__ rowptr, const int* __restrict__ csr,
    float* __restrict__ hout, ushort_t* __restrict__ hhi, ushort_t* __restrict__ hlo)
{
    const int wave = threadIdx.x >> 6;
    const int lane = threadIdx.x & 63;
    const int n = blockIdx.x * 4 + wave;
    if (n >= NN) return;
    const int h  = lane >> 2;
    const int cc = lane & 3;
    const int cb = h * NH + cc * 16;          // col base within [16*64]

    float attv[16], xrv[16], acc[16];
    #pragma unroll
    for (int i = 0; i < 4; ++i)
        *(float4*)(attv + i * 4) = *(const float4*)(att + cb + i * 4);
    const float* xrp = xr + (size_t)n * 1024 + cb;
    #pragma unroll
    for (int i = 0; i < 4; ++i)
        *(float4*)(xrv + i * 4) = *(const float4*)(xrp + i * 4);
    #pragma unroll
    for (int j = 0; j < 16; ++j) acc[j] = 0.f;

    float m = -INFINITY, den = 0.f;
    const int e0 = rowptr[n], e1 = rowptr[n + 1];
    for (int e = e0; e < e1; ++e) {
        const int s = csr[e];
        const float* xlp = xl + (size_t)s * 1024 + cb;
        float xlv[16];
        #pragma unroll
        for (int i = 0; i < 4; ++i)
            *(float4*)(xlv + i * 4) = *(const float4*)(xlp + i * 4);
        float partial = 0.f;
        #pragma unroll
        for (int j = 0; j < 16; ++j) {
            float tt = xlv[j] + xrv[j];
            tt = fmaxf(tt, 0.2f * tt);                   // LeakyReLU(0.2)
            partial = fmaf(tt, attv[j], partial);
        }
        partial += __shfl_xor(partial, 1);
        partial += __shfl_xor(partial, 2);               // logit, replicated x4
        const float nm = fmaxf(m, partial);
        const float p  = __expf(partial - nm);
        const float sc = __expf(m - nm);                 // exp(-inf)=0 first iter
        den = den * sc + p;
        #pragma unroll
        for (int j = 0; j < 16; ++j)
            acc[j] = fmaf(acc[j], sc, p * xlv[j]);
        m = nm;
    }

    const float inv = 1.f / den;
    float v[16];
    #pragma unroll
    for (int j = 0; j < 16; ++j) v[j] = acc[j] * inv;
    #pragma unroll
    for (int mask = 4; mask <= 32; mask <<= 1)
        #pragma unroll
        for (int j = 0; j < 16; ++j) v[j] += __shfl_xor(v[j], mask);

    if (h == 0) {                                        // lanes 0..3 hold head-sums
        float bvv[16];
        #pragma unroll
        for (int i = 0; i < 4; ++i)
            *(float4*)(bvv + i * 4) = *(const float4*)(bias + cc * 16 + i * 4);
        #pragma unroll
        for (int i = 0; i < 4; ++i) {
            float o[4];
            #pragma unroll
            for (int r = 0; r < 4; ++r) {
                float tt = v[i * 4 + r] * 0.0625f + bvv[i * 4 + r];
                o[r] = fmaxf(tt, 0.01f * tt);            // out LeakyReLU(0.01)
            }
            if (SPLIT) {
                ushort4 hh, ll;
                hh.x = f2bf_rn(o[0]); ll.x = f2bf_rn(o[0] - bf2f(hh.x));
                hh.y = f2bf_rn(o[1]); ll.y = f2bf_rn(o[1] - bf2f(hh.y));
                hh.z = f2bf_rn(o[2]); ll.z = f2bf_rn(o[2] - bf2f(hh.z));
                hh.w = f2bf_rn(o[3]); ll.w = f2bf_rn(o[3] - bf2f(hh.w));
                *(ushort4*)(hhi + (size_t)n * NH + cc * 16 + i * 4) = hh;
                *(ushort4*)(hlo + (size_t)n * NH + cc * 16 + i * 4) = ll;
            } else {
                *(float4*)(hout + (size_t)n * NH + cc * 16 + i * 4) =
                    make_float4(o[0], o[1], o[2], o[3]);
            }
        }
    }
}

// ---------------------------------------------------------------- pool + heads
__global__ void k_pool(const float* __restrict__ h2, const int* __restrict__ bstart,
                       const float* __restrict__ Wc, const float* __restrict__ bc,
                       const float* __restrict__ Wv, const float* __restrict__ bv,
                       float* __restrict__ out)
{
    const int b = blockIdx.x, c = threadIdx.x;   // 64 threads
    const int s = bstart[b], e = bstart[b + 1];
    float sum = 0.f;
    for (int n = s; n < e; ++n) sum += h2[(size_t)n * NH + c];
    const float cnt = (float)(e - s);
    const float pooled = sum / fmaxf(cnt, 1.f);
    __shared__ float pl[NH];
    pl[c] = pooled;
    __syncthreads();
    if (c < NCLS) {
        float a = bc[c];
        for (int k = 0; k < NH; ++k) a = fmaf(pl[k], Wc[k * NCLS + c], a);
        out[b * NCLS + c] = a;
    } else if (c == NCLS) {
        float a = bv[0];
        for (int k = 0; k < NH; ++k) a = fmaf(pl[k], Wv[k], a);
        out[NBAT * NCLS + b] = a;
    }
}

// ---------------------------------------------------------------- launch
extern "C" void kernel_launch(void* const* d_in, const int* in_sizes, int n_in,
                              void* d_out, int out_size, void* d_ws, size_t ws_size,
                              hipStream_t stream)
{
    const float* x     = (const float*)d_in[0];
    const int*   ei    = (const int*)  d_in[1];
    const int*   batch = (const int*)  d_in[2];
    const float* W1l = (const float*)d_in[3],  *b1l = (const float*)d_in[4];
    const float* W1r = (const float*)d_in[5],  *b1r = (const float*)d_in[6];
    const float* att1 = (const float*)d_in[7], *bias1 = (const float*)d_in[8];
    const float* W2l = (const float*)d_in[9],  *b2l = (const float*)d_in[10];
    const float* W2r = (const float*)d_in[11], *b2r = (const float*)d_in[12];
    const float* att2 = (const float*)d_in[13], *bias2 = (const float*)d_in[14];
    const float* Wc = (const float*)d_in[15],  *bc = (const float*)d_in[16];
    const float* Wv = (const float*)d_in[17],  *bv = (const float*)d_in[18];
    float* out = (float*)d_out;

    char* ws = (char*)d_ws;
    size_t off = 0;
    auto carve = [&](size_t bytes) {
        char* p = ws + off;
        off = (off + bytes + 255) & ~(size_t)255;
        return p;
    };
    float*    xl    = (float*)carve((size_t)NN * 1024 * 4);
    float*    xr    = (float*)carve((size_t)NN * 1024 * 4);
    float*    h2    = (float*)carve((size_t)NN * NH * 4);
    ushort_t* Axhi  = (ushort_t*)carve((size_t)NN * NF * 2);
    ushort_t* Axlo  = (ushort_t*)carve((size_t)NN * NF * 2);
    ushort_t* h1hi  = (ushort_t*)carve((size_t)NN * NH * 2);
    ushort_t* h1lo  = (ushort_t*)carve((size_t)NN * NH * 2);
    ushort_t* Wt1lh = (ushort_t*)carve((size_t)1024 * NF * 2);
    ushort_t* Wt1ll = (ushort_t*)carve((size_t)1024 * NF * 2);
    ushort_t* Wt1rh = (ushort_t*)carve((size_t)1024 * NF * 2);
    ushort_t* Wt1rl = (ushort_t*)carve((size_t)1024 * NF * 2);
    ushort_t* Wt2lh = (ushort_t*)carve((size_t)1024 * NH * 2);
    ushort_t* Wt2ll = (ushort_t*)carve((size_t)1024 * NH * 2);
    ushort_t* Wt2rh = (ushort_t*)carve((size_t)1024 * NH * 2);
    ushort_t* Wt2rl = (ushort_t*)carve((size_t)1024 * NH * 2);
    int*      deg    = (int*)carve((size_t)NN * 4);
    int*      cursor = (int*)carve((size_t)NN * 4);
    int*      rowptr = (int*)carve((size_t)(NN + 1) * 4);
    int*      csr    = (int*)carve((size_t)ETOT * 4);
    int*      bstart = (int*)carve((size_t)(NBAT + 1) * 4);

    // graph preprocessing
    k_init_deg<<<(NN + 255) / 256, 256, 0, stream>>>(deg);
    k_hist   <<<(EE + 255) / 256, 256, 0, stream>>>(ei, deg);
    k_scan   <<<1, 1024, 0, stream>>>(deg, rowptr, cursor);
    k_scatter<<<(ETOT + 255) / 256, 256, 0, stream>>>(ei, cursor, csr);
    k_bounds <<<(NN + 255) / 256, 256, 0, stream>>>(batch, bstart);

    // input splits
    k_split_a<<<(NN * NF / 4 + 255) / 256, 256, 0, stream>>>(x, Axhi, Axlo, NN * NF / 4);
    k_split_w<NF><<<(NF * 1024 + 255) / 256, 256, 0, stream>>>(W1l, Wt1lh, Wt1ll);
    k_split_w<NF><<<(NF * 1024 + 255) / 256, 256, 0, stream>>>(W1r, Wt1rh, Wt1rl);
    k_split_w<NH><<<(NH * 1024 + 255) / 256, 256, 0, stream>>>(W2l, Wt2lh, Wt2ll);
    k_split_w<NH><<<(NH * 1024 + 255) / 256, 256, 0, stream>>>(W2r, Wt2rh, Wt2rl);

    const int MB = (NN + 127) / 128;   // 157 row blocks
    // layer 1
    k_gemm_mfma<NF><<<dim3(MB, 8, 2), 256, 0, stream>>>(
        Axhi, Axlo, NN, Wt1lh, Wt1ll, b1l, xl, Wt1rh, Wt1rl, b1r, xr);
    k_attn<1><<<NN / 4, 256, 0, stream>>>(xl, xr, att1, bias1, rowptr, csr,
                                          (float*)nullptr, h1hi, h1lo);
    // layer 2
    k_gemm_mfma<NH><<<dim3(MB, 8, 2), 256, 0, stream>>>(
        h1hi, h1lo, NN, Wt2lh, Wt2ll, b2l, xl, Wt2rh, Wt2rl, b2r, xr);
    k_attn<0><<<NN / 4, 256, 0, stream>>>(xl, xr, att2, bias2, rowptr, csr,
                                          h2, (ushort_t*)nullptr, (ushort_t*)nullptr);
    // pool + heads
    k_pool<<<NBAT, NH, 0, stream>>>(h2, bstart, Wc, bc, Wv, bv, out);
}

// Round 4
// 456.322 us; speedup vs baseline: 1.4970x; 1.2318x over previous
//
#include <hip/hip_runtime.h>
#include <hip/hip_bf16.h>
#include <hip/hip_fp16.h>
#include <math.h>

#define NN   20000
#define EE   160000
#define NBAT 64
#define NF   128
#define NH   64
#define NHEAD 16
#define NCLS 10
#define ETOT (EE + NN)   // edges + self loops = 180000

typedef __attribute__((ext_vector_type(8))) short short8;
typedef __attribute__((ext_vector_type(8))) _Float16 half8;
typedef __attribute__((ext_vector_type(4))) float f32x4;
typedef unsigned short ushort_t;

// bf16 helpers (bit-level, RNE; no NaN in our data)
static __device__ __forceinline__ ushort_t f2bf_rn(float x) {
    unsigned u = __builtin_bit_cast(unsigned, x);
    unsigned r = (u + 0x7fffu + ((u >> 16) & 1u)) >> 16;
    return (ushort_t)r;
}
static __device__ __forceinline__ float bf2f(ushort_t u) {
    unsigned v = (unsigned)u << 16;
    return __builtin_bit_cast(float, v);
}

// ---------------------------------------------------------------- CSR build
__global__ void k_init_deg(int* __restrict__ deg) {
    int n = blockIdx.x * 256 + threadIdx.x;
    if (n < NN) deg[n] = 1;                 // self-loop
}

__global__ void k_hist(const int* __restrict__ ei, int* __restrict__ deg) {
    int e = blockIdx.x * 256 + threadIdx.x;
    if (e < EE) atomicAdd(&deg[ei[EE + e]], 1);   // dst row
}

__global__ void k_scan(const int* __restrict__ deg, int* __restrict__ rowptr,
                       int* __restrict__ cursor) {
    const int T = 1024, PER = (NN + T - 1) / T;   // 20
    __shared__ int part[T];
    int t = threadIdx.x;
    int local[PER];
    int s = 0;
    #pragma unroll
    for (int i = 0; i < PER; ++i) {
        int idx = t * PER + i;
        int v = (idx < NN) ? deg[idx] : 0;
        local[i] = v; s += v;
    }
    part[t] = s;
    __syncthreads();
    for (int off = 1; off < T; off <<= 1) {
        int v = (t >= off) ? part[t - off] : 0;
        __syncthreads();
        part[t] += v;
        __syncthreads();
    }
    int ex = (t == 0) ? 0 : part[t - 1];
    #pragma unroll
    for (int i = 0; i < PER; ++i) {
        int idx = t * PER + i;
        if (idx < NN) { rowptr[idx] = ex; cursor[idx] = ex; ex += local[i]; }
    }
    if (t == T - 1) rowptr[NN] = ex;
}

__global__ void k_scatter(const int* __restrict__ ei, int* __restrict__ cursor,
                          int* __restrict__ csr) {
    int e = blockIdx.x * 256 + threadIdx.x;
    if (e >= ETOT) return;
    int s, d;
    if (e < EE) { s = ei[e]; d = ei[EE + e]; }
    else        { s = e - EE; d = s; }
    int pos = atomicAdd(&cursor[d], 1);
    csr[pos] = s;
}

__global__ void k_bounds(const int* __restrict__ batch, int* __restrict__ bstart) {
    int n = blockIdx.x * 256 + threadIdx.x;
    if (n >= NN) return;
    int b = batch[n];
    if (n == 0) for (int bb = 0; bb <= b; ++bb) bstart[bb] = 0;
    int bn = (n + 1 < NN) ? batch[n + 1] : NBAT;
    for (int bb = b + 1; bb <= bn; ++bb) bstart[bb] = n + 1;
}

// ---------------------------------------------------------------- splits
// A [count] fp32 -> hi/lo bf16 (same layout), vectorized x4
__global__ void k_split_a(const float* __restrict__ A, ushort_t* __restrict__ hi,
                          ushort_t* __restrict__ lo, int count4) {
    int idx = blockIdx.x * 256 + threadIdx.x;
    if (idx >= count4) return;
    float4 x = *(const float4*)(A + idx * 4);
    ushort4 h, l;
    h.x = f2bf_rn(x.x); l.x = f2bf_rn(x.x - bf2f(h.x));
    h.y = f2bf_rn(x.y); l.y = f2bf_rn(x.y - bf2f(h.y));
    h.z = f2bf_rn(x.z); l.z = f2bf_rn(x.z - bf2f(h.z));
    h.w = f2bf_rn(x.w); l.w = f2bf_rn(x.w - bf2f(h.w));
    *(ushort4*)(hi + idx * 4) = h;
    *(ushort4*)(lo + idx * 4) = l;
}

// W [K][1024] fp32 -> Wt hi/lo [1024][K] bf16 (transposed)
template<int K>
__global__ void k_split_w(const float* __restrict__ W, ushort_t* __restrict__ hi,
                          ushort_t* __restrict__ lo) {
    int idx = blockIdx.x * 256 + threadIdx.x;
    if (idx >= K * 1024) return;
    int k = idx >> 10, n = idx & 1023;
    float x = W[idx];
    ushort_t h = f2bf_rn(x);
    hi[n * K + k] = h;
    lo[n * K + k] = f2bf_rn(x - bf2f(h));
}

// ------------------------------------------------- split-bf16 MFMA GEMM
// O[M][1024] = split(A)[M][K] @ split(W)[K][1024] + b  (3-term: hh + hl + lh)
// Output stored as fp16. Wt layouts transposed: [1024][K]. blockIdx.z selects.
template<int K>
__global__ __launch_bounds__(256) void k_gemm_mfma(
    const ushort_t* __restrict__ Ahi, const ushort_t* __restrict__ Alo, int M,
    const ushort_t* __restrict__ W0hi, const ushort_t* __restrict__ W0lo,
    const float* __restrict__ b0, _Float16* __restrict__ O0,
    const ushort_t* __restrict__ W1hi, const ushort_t* __restrict__ W1lo,
    const float* __restrict__ b1, _Float16* __restrict__ O1)
{
    const ushort_t* Whi = blockIdx.z ? W1hi : W0hi;
    const ushort_t* Wlo = blockIdx.z ? W1lo : W0lo;
    const float*    bi  = blockIdx.z ? b1 : b0;
    _Float16*       O   = blockIdx.z ? O1 : O0;

    const int r0 = blockIdx.x * 128;
    const int c0 = blockIdx.y * 128;

    __shared__ __align__(16) ushort_t As_hi[128 * 64];
    __shared__ __align__(16) ushort_t As_lo[128 * 64];
    __shared__ __align__(16) ushort_t Ws_hi[128 * 64];
    __shared__ __align__(16) ushort_t Ws_lo[128 * 64];

    const int t = threadIdx.x;
    const int lane = t & 63;
    const int wv = t >> 6, wr = wv >> 1, wc = wv & 1;
    const int fr = lane & 15;            // fragment row/col
    const int k0 = (lane >> 4) * 8;      // k-slice within 32

    f32x4 acc[4][4] = {};

    for (int kt = 0; kt < K; kt += 64) {
        // ---- stage (reg -> LDS, XOR-swizzled writes) ----
        #pragma unroll
        for (int p = 0; p < 4; ++p) {
            int idx = p * 256 + t;       // 0..1023
            int m  = idx >> 3;           // 0..127
            int kc = (idx & 7) * 8;      // 0..56
            int gr = r0 + m;
            uint4 vh = make_uint4(0, 0, 0, 0), vl = make_uint4(0, 0, 0, 0);
            if (gr < M) {
                vh = *(const uint4*)(Ahi + (size_t)gr * K + kt + kc);
                vl = *(const uint4*)(Alo + (size_t)gr * K + kt + kc);
            }
            int sw = (m * 128 + kc * 2) ^ ((m & 7) << 4);
            *(uint4*)((char*)As_hi + sw) = vh;
            *(uint4*)((char*)As_lo + sw) = vl;
            uint4 wh = *(const uint4*)(Whi + (size_t)(c0 + m) * K + kt + kc);
            uint4 wl = *(const uint4*)(Wlo + (size_t)(c0 + m) * K + kt + kc);
            *(uint4*)((char*)Ws_hi + sw) = wh;
            *(uint4*)((char*)Ws_lo + sw) = wl;
        }
        __syncthreads();

        // ---- MFMA ----
        #pragma unroll
        for (int ks = 0; ks < 64; ks += 32) {
            short8 ah[4], al[4], bh[4], bl[4];
            #pragma unroll
            for (int i = 0; i < 4; ++i) {
                int row = wr * 64 + i * 16 + fr;
                int off = (row * 128 + (ks + k0) * 2) ^ ((row & 7) << 4);
                ah[i] = *(const short8*)((const char*)As_hi + off);
                al[i] = *(const short8*)((const char*)As_lo + off);
            }
            #pragma unroll
            for (int j = 0; j < 4; ++j) {
                int col = wc * 64 + j * 16 + fr;
                int off = (col * 128 + (ks + k0) * 2) ^ ((col & 7) << 4);
                bh[j] = *(const short8*)((const char*)Ws_hi + off);
                bl[j] = *(const short8*)((const char*)Ws_lo + off);
            }
            #pragma unroll
            for (int i = 0; i < 4; ++i)
                #pragma unroll
                for (int j = 0; j < 4; ++j) {
                    acc[i][j] = __builtin_amdgcn_mfma_f32_16x16x32_bf16(ah[i], bh[j], acc[i][j], 0, 0, 0);
                    acc[i][j] = __builtin_amdgcn_mfma_f32_16x16x32_bf16(ah[i], bl[j], acc[i][j], 0, 0, 0);
                    acc[i][j] = __builtin_amdgcn_mfma_f32_16x16x32_bf16(al[i], bh[j], acc[i][j], 0, 0, 0);
                }
        }
        __syncthreads();
    }

    // ---- epilogue: + bias, convert to fp16, store ----
    float bj[4];
    #pragma unroll
    for (int j = 0; j < 4; ++j) bj[j] = bi[c0 + wc * 64 + j * 16 + fr];
    #pragma unroll
    for (int i = 0; i < 4; ++i) {
        int rbase = r0 + wr * 64 + i * 16 + (lane >> 4) * 4;
        #pragma unroll
        for (int r = 0; r < 4; ++r) {
            int gr = rbase + r;
            if (gr < M) {
                #pragma unroll
                for (int j = 0; j < 4; ++j)
                    O[(size_t)gr * 1024 + c0 + wc * 64 + j * 16 + fr] =
                        (_Float16)(acc[i][j][r] + bj[j]);
            }
        }
    }
}

// ------------------------------------------------- attention + aggregation
// one wave per node; lane = (head h = lane>>2, c-chunk cc = lane&3, 16 c each)
// xl/xr are fp16. SPLIT=1: write bf16 hi/lo; SPLIT=0: write fp32.
template<int SPLIT>
__global__ __launch_bounds__(256) void k_attn(
    const _Float16* __restrict__ xl, const _Float16* __restrict__ xr,
    const float* __restrict__ att, const float* __restrict__ bias,
    const int* __restrict__ rowptr, const int* __restrict__ csr,
    float* __restrict__ hout, ushort_t* __restrict__ hhi, ushort_t* __restrict__ hlo)
{
    const int wave = threadIdx.x >> 6;
    const int lane = threadIdx.x & 63;
    const int n = blockIdx.x * 4 + wave;
    if (n >= NN) return;
    const int h  = lane >> 2;
    const int cc = lane & 3;
    const int cb = h * NH + cc * 16;          // col base within [16*64]

    float attv[16], xrv[16], acc[16];
    #pragma unroll
    for (int i = 0; i < 4; ++i)
        *(float4*)(attv + i * 4) = *(const float4*)(att + cb + i * 4);
    {
        half8 q0 = *(const half8*)(xr + (size_t)n * 1024 + cb);
        half8 q1 = *(const half8*)(xr + (size_t)n * 1024 + cb + 8);
        #pragma unroll
        for (int j = 0; j < 8; ++j) { xrv[j] = (float)q0[j]; xrv[8 + j] = (float)q1[j]; }
    }
    #pragma unroll
    for (int j = 0; j < 16; ++j) acc[j] = 0.f;

    float m = -INFINITY, den = 0.f;
    const int e0 = rowptr[n], e1 = rowptr[n + 1];
    int e = e0;

    // 2-edge unrolled main loop (ILP on the gather loads)
    for (; e + 2 <= e1; e += 2) {
        const int s0 = csr[e], s1 = csr[e + 1];
        const _Float16* p0 = xl + (size_t)s0 * 1024 + cb;
        const _Float16* p1 = xl + (size_t)s1 * 1024 + cb;
        half8 a0 = *(const half8*)p0;
        half8 a1 = *(const half8*)(p0 + 8);
        half8 b0 = *(const half8*)p1;
        half8 b1 = *(const half8*)(p1 + 8);
        float x0[16], x1[16];
        #pragma unroll
        for (int j = 0; j < 8; ++j) {
            x0[j] = (float)a0[j]; x0[8 + j] = (float)a1[j];
            x1[j] = (float)b0[j]; x1[8 + j] = (float)b1[j];
        }
        float l0 = 0.f, l1 = 0.f;
        #pragma unroll
        for (int j = 0; j < 16; ++j) {
            float t0 = x0[j] + xrv[j];
            float t1 = x1[j] + xrv[j];
            t0 = fmaxf(t0, 0.2f * t0);
            t1 = fmaxf(t1, 0.2f * t1);
            l0 = fmaf(t0, attv[j], l0);
            l1 = fmaf(t1, attv[j], l1);
        }
        l0 += __shfl_xor(l0, 1); l1 += __shfl_xor(l1, 1);
        l0 += __shfl_xor(l0, 2); l1 += __shfl_xor(l1, 2);
        // sequential online-softmax updates (values already in regs)
        {
            const float nm = fmaxf(m, l0);
            const float p  = __expf(l0 - nm);
            const float sc = __expf(m - nm);
            den = den * sc + p;
            #pragma unroll
            for (int j = 0; j < 16; ++j) acc[j] = fmaf(acc[j], sc, p * x0[j]);
            m = nm;
        }
        {
            const float nm = fmaxf(m, l1);
            const float p  = __expf(l1 - nm);
            const float sc = __expf(m - nm);
            den = den * sc + p;
            #pragma unroll
            for (int j = 0; j < 16; ++j) acc[j] = fmaf(acc[j], sc, p * x1[j]);
            m = nm;
        }
    }
    // tail edge
    for (; e < e1; ++e) {
        const int s = csr[e];
        const _Float16* p0 = xl + (size_t)s * 1024 + cb;
        half8 a0 = *(const half8*)p0;
        half8 a1 = *(const half8*)(p0 + 8);
        float x0[16];
        #pragma unroll
        for (int j = 0; j < 8; ++j) { x0[j] = (float)a0[j]; x0[8 + j] = (float)a1[j]; }
        float l0 = 0.f;
        #pragma unroll
        for (int j = 0; j < 16; ++j) {
            float t0 = x0[j] + xrv[j];
            t0 = fmaxf(t0, 0.2f * t0);
            l0 = fmaf(t0, attv[j], l0);
        }
        l0 += __shfl_xor(l0, 1);
        l0 += __shfl_xor(l0, 2);
        const float nm = fmaxf(m, l0);
        const float p  = __expf(l0 - nm);
        const float sc = __expf(m - nm);
        den = den * sc + p;
        #pragma unroll
        for (int j = 0; j < 16; ++j) acc[j] = fmaf(acc[j], sc, p * x0[j]);
        m = nm;
    }

    const float inv = 1.f / den;
    float v[16];
    #pragma unroll
    for (int j = 0; j < 16; ++j) v[j] = acc[j] * inv;
    #pragma unroll
    for (int mask = 4; mask <= 32; mask <<= 1)
        #pragma unroll
        for (int j = 0; j < 16; ++j) v[j] += __shfl_xor(v[j], mask);

    if (h == 0) {                                        // lanes 0..3 hold head-sums
        float bvv[16];
        #pragma unroll
        for (int i = 0; i < 4; ++i)
            *(float4*)(bvv + i * 4) = *(const float4*)(bias + cc * 16 + i * 4);
        #pragma unroll
        for (int i = 0; i < 4; ++i) {
            float o[4];
            #pragma unroll
            for (int r = 0; r < 4; ++r) {
                float tt = v[i * 4 + r] * 0.0625f + bvv[i * 4 + r];
                o[r] = fmaxf(tt, 0.01f * tt);            // out LeakyReLU(0.01)
            }
            if (SPLIT) {
                ushort4 hh, ll;
                hh.x = f2bf_rn(o[0]); ll.x = f2bf_rn(o[0] - bf2f(hh.x));
                hh.y = f2bf_rn(o[1]); ll.y = f2bf_rn(o[1] - bf2f(hh.y));
                hh.z = f2bf_rn(o[2]); ll.z = f2bf_rn(o[2] - bf2f(hh.z));
                hh.w = f2bf_rn(o[3]); ll.w = f2bf_rn(o[3] - bf2f(hh.w));
                *(ushort4*)(hhi + (size_t)n * NH + cc * 16 + i * 4) = hh;
                *(ushort4*)(hlo + (size_t)n * NH + cc * 16 + i * 4) = ll;
            } else {
                *(float4*)(hout + (size_t)n * NH + cc * 16 + i * 4) =
                    make_float4(o[0], o[1], o[2], o[3]);
            }
        }
    }
}

// ---------------------------------------------------------------- pool + heads
__global__ void k_pool(const float* __restrict__ h2, const int* __restrict__ bstart,
                       const float* __restrict__ Wc, const float* __restrict__ bc,
                       const float* __restrict__ Wv, const float* __restrict__ bv,
                       float* __restrict__ out)
{
    const int b = blockIdx.x, c = threadIdx.x;   // 64 threads
    const int s = bstart[b], e = bstart[b + 1];
    float sum = 0.f;
    for (int n = s; n < e; ++n) sum += h2[(size_t)n * NH + c];
    const float cnt = (float)(e - s);
    const float pooled = sum / fmaxf(cnt, 1.f);
    __shared__ float pl[NH];
    pl[c] = pooled;
    __syncthreads();
    if (c < NCLS) {
        float a = bc[c];
        for (int k = 0; k < NH; ++k) a = fmaf(pl[k], Wc[k * NCLS + c], a);
        out[b * NCLS + c] = a;
    } else if (c == NCLS) {
        float a = bv[0];
        for (int k = 0; k < NH; ++k) a = fmaf(pl[k], Wv[k], a);
        out[NBAT * NCLS + b] = a;
    }
}

// ---------------------------------------------------------------- launch
extern "C" void kernel_launch(void* const* d_in, const int* in_sizes, int n_in,
                              void* d_out, int out_size, void* d_ws, size_t ws_size,
                              hipStream_t stream)
{
    const float* x     = (const float*)d_in[0];
    const int*   ei    = (const int*)  d_in[1];
    const int*   batch = (const int*)  d_in[2];
    const float* W1l = (const float*)d_in[3],  *b1l = (const float*)d_in[4];
    const float* W1r = (const float*)d_in[5],  *b1r = (const float*)d_in[6];
    const float* att1 = (const float*)d_in[7], *bias1 = (const float*)d_in[8];
    const float* W2l = (const float*)d_in[9],  *b2l = (const float*)d_in[10];
    const float* W2r = (const float*)d_in[11], *b2r = (const float*)d_in[12];
    const float* att2 = (const float*)d_in[13], *bias2 = (const float*)d_in[14];
    const float* Wc = (const float*)d_in[15],  *bc = (const float*)d_in[16];
    const float* Wv = (const float*)d_in[17],  *bv = (const float*)d_in[18];
    float* out = (float*)d_out;

    char* ws = (char*)d_ws;
    size_t off = 0;
    auto carve = [&](size_t bytes) {
        char* p = ws + off;
        off = (off + bytes + 255) & ~(size_t)255;
        return p;
    };
    _Float16* xl    = (_Float16*)carve((size_t)NN * 1024 * 2);
    _Float16* xr    = (_Float16*)carve((size_t)NN * 1024 * 2);
    float*    h2    = (float*)carve((size_t)NN * NH * 4);
    ushort_t* Axhi  = (ushort_t*)carve((size_t)NN * NF * 2);
    ushort_t* Axlo  = (ushort_t*)carve((size_t)NN * NF * 2);
    ushort_t* h1hi  = (ushort_t*)carve((size_t)NN * NH * 2);
    ushort_t* h1lo  = (ushort_t*)carve((size_t)NN * NH * 2);
    ushort_t* Wt1lh = (ushort_t*)carve((size_t)1024 * NF * 2);
    ushort_t* Wt1ll = (ushort_t*)carve((size_t)1024 * NF * 2);
    ushort_t* Wt1rh = (ushort_t*)carve((size_t)1024 * NF * 2);
    ushort_t* Wt1rl = (ushort_t*)carve((size_t)1024 * NF * 2);
    ushort_t* Wt2lh = (ushort_t*)carve((size_t)1024 * NH * 2);
    ushort_t* Wt2ll = (ushort_t*)carve((size_t)1024 * NH * 2);
    ushort_t* Wt2rh = (ushort_t*)carve((size_t)1024 * NH * 2);
    ushort_t* Wt2rl = (ushort_t*)carve((size_t)1024 * NH * 2);
    int*      deg    = (int*)carve((size_t)NN * 4);
    int*      cursor = (int*)carve((size_t)NN * 4);
    int*      rowptr = (int*)carve((size_t)(NN + 1) * 4);
    int*      csr    = (int*)carve((size_t)ETOT * 4);
    int*      bstart = (int*)carve((size_t)(NBAT + 1) * 4);

    // graph preprocessing
    k_init_deg<<<(NN + 255) / 256, 256, 0, stream>>>(deg);
    k_hist   <<<(EE + 255) / 256, 256, 0, stream>>>(ei, deg);
    k_scan   <<<1, 1024, 0, stream>>>(deg, rowptr, cursor);
    k_scatter<<<(ETOT + 255) / 256, 256, 0, stream>>>(ei, cursor, csr);
    k_bounds <<<(NN + 255) / 256, 256, 0, stream>>>(batch, bstart);

    // input splits
    k_split_a<<<(NN * NF / 4 + 255) / 256, 256, 0, stream>>>(x, Axhi, Axlo, NN * NF / 4);
    k_split_w<NF><<<(NF * 1024 + 255) / 256, 256, 0, stream>>>(W1l, Wt1lh, Wt1ll);
    k_split_w<NF><<<(NF * 1024 + 255) / 256, 256, 0, stream>>>(W1r, Wt1rh, Wt1rl);
    k_split_w<NH><<<(NH * 1024 + 255) / 256, 256, 0, stream>>>(W2l, Wt2lh, Wt2ll);
    k_split_w<NH><<<(NH * 1024 + 255) / 256, 256, 0, stream>>>(W2r, Wt2rh, Wt2rl);

    const int MB = (NN + 127) / 128;   // 157 row blocks
    // layer 1
    k_gemm_mfma<NF><<<dim3(MB, 8, 2), 256, 0, stream>>>(
        Axhi, Axlo, NN, Wt1lh, Wt1ll, b1l, xl, Wt1rh, Wt1rl, b1r, xr);
    k_attn<1><<<NN / 4, 256, 0, stream>>>(xl, xr, att1, bias1, rowptr, csr,
                                          (float*)nullptr, h1hi, h1lo);
    // layer 2
    k_gemm_mfma<NH><<<dim3(MB, 8, 2), 256, 0, stream>>>(
        h1hi, h1lo, NN, Wt2lh, Wt2ll, b2l, xl, Wt2rh, Wt2rl, b2r, xr);
    k_attn<0><<<NN / 4, 256, 0, stream>>>(xl, xr, att2, bias2, rowptr, csr,
                                          h2, (ushort_t*)nullptr, (ushort_t*)nullptr);
    // pool + heads
    k_pool<<<NBAT, NH, 0, stream>>>(h2, bstart, Wc, bc, Wv, bv, out);
}

// Round 5
// 387.097 us; speedup vs baseline: 1.7647x; 1.1788x over previous
//
#include <hip/hip_runtime.h>
#include <hip/hip_bf16.h>
#include <hip/hip_fp16.h>
#include <math.h>

#define NN   20000
#define EE   160000
#define NBAT 64
#define NF   128
#define NH   64
#define NHEAD 16
#define NCLS 10
#define ETOT (EE + NN)   // edges + self loops = 180000

typedef __attribute__((ext_vector_type(8))) short short8;
typedef __attribute__((ext_vector_type(8))) _Float16 half8;
typedef __attribute__((ext_vector_type(4))) float f32x4;
typedef unsigned short ushort_t;

// bf16 helpers (bit-level, RNE; no NaN in our data)
static __device__ __forceinline__ ushort_t f2bf_rn(float x) {
    unsigned u = __builtin_bit_cast(unsigned, x);
    unsigned r = (u + 0x7fffu + ((u >> 16) & 1u)) >> 16;
    return (ushort_t)r;
}
static __device__ __forceinline__ float bf2f(ushort_t u) {
    unsigned v = (unsigned)u << 16;
    return __builtin_bit_cast(float, v);
}

// ---------------------------------------------------------------- CSR build
__global__ void k_init_deg(int* __restrict__ deg) {
    int n = blockIdx.x * 256 + threadIdx.x;
    if (n < NN) deg[n] = 1;                 // self-loop
}

__global__ void k_hist(const int* __restrict__ ei, int* __restrict__ deg) {
    int e = blockIdx.x * 256 + threadIdx.x;
    if (e < EE) atomicAdd(&deg[ei[EE + e]], 1);   // dst row
}

__global__ void k_scan(const int* __restrict__ deg, int* __restrict__ rowptr,
                       int* __restrict__ cursor) {
    const int T = 1024, PER = (NN + T - 1) / T;   // 20
    __shared__ int part[T];
    int t = threadIdx.x;
    int local[PER];
    int s = 0;
    #pragma unroll
    for (int i = 0; i < PER; ++i) {
        int idx = t * PER + i;
        int v = (idx < NN) ? deg[idx] : 0;
        local[i] = v; s += v;
    }
    part[t] = s;
    __syncthreads();
    for (int off = 1; off < T; off <<= 1) {
        int v = (t >= off) ? part[t - off] : 0;
        __syncthreads();
        part[t] += v;
        __syncthreads();
    }
    int ex = (t == 0) ? 0 : part[t - 1];
    #pragma unroll
    for (int i = 0; i < PER; ++i) {
        int idx = t * PER + i;
        if (idx < NN) { rowptr[idx] = ex; cursor[idx] = ex; ex += local[i]; }
    }
    if (t == T - 1) rowptr[NN] = ex;
}

__global__ void k_scatter(const int* __restrict__ ei, int* __restrict__ cursor,
                          int* __restrict__ csr) {
    int e = blockIdx.x * 256 + threadIdx.x;
    if (e >= ETOT) return;
    int s, d;
    if (e < EE) { s = ei[e]; d = ei[EE + e]; }
    else        { s = e - EE; d = s; }
    int pos = atomicAdd(&cursor[d], 1);
    csr[pos] = s;
}

__global__ void k_bounds(const int* __restrict__ batch, int* __restrict__ bstart) {
    int n = blockIdx.x * 256 + threadIdx.x;
    if (n >= NN) return;
    int b = batch[n];
    if (n == 0) for (int bb = 0; bb <= b; ++bb) bstart[bb] = 0;
    int bn = (n + 1 < NN) ? batch[n + 1] : NBAT;
    for (int bb = b + 1; bb <= bn; ++bb) bstart[bb] = n + 1;
}

// ---------------------------------------------------------------- splits
// A [count] fp32 -> hi/lo bf16 (same layout), vectorized x4
__global__ void k_split_a(const float* __restrict__ A, ushort_t* __restrict__ hi,
                          ushort_t* __restrict__ lo, int count4) {
    int idx = blockIdx.x * 256 + threadIdx.x;
    if (idx >= count4) return;
    float4 x = *(const float4*)(A + idx * 4);
    ushort4 h, l;
    h.x = f2bf_rn(x.x); l.x = f2bf_rn(x.x - bf2f(h.x));
    h.y = f2bf_rn(x.y); l.y = f2bf_rn(x.y - bf2f(h.y));
    h.z = f2bf_rn(x.z); l.z = f2bf_rn(x.z - bf2f(h.z));
    h.w = f2bf_rn(x.w); l.w = f2bf_rn(x.w - bf2f(h.w));
    *(ushort4*)(hi + idx * 4) = h;
    *(ushort4*)(lo + idx * 4) = l;
}

// W [K][1024] fp32 -> Wt hi/lo [1024][K] bf16 (transposed)
template<int K>
__global__ void k_split_w(const float* __restrict__ W, ushort_t* __restrict__ hi,
                          ushort_t* __restrict__ lo) {
    int idx = blockIdx.x * 256 + threadIdx.x;
    if (idx >= K * 1024) return;
    int k = idx >> 10, n = idx & 1023;
    float x = W[idx];
    ushort_t h = f2bf_rn(x);
    hi[n * K + k] = h;
    lo[n * K + k] = f2bf_rn(x - bf2f(h));
}

// ------------------------------------------------- split-bf16 MFMA GEMM
// O[M][1024] = split(A)[M][K] @ split(W)[K][1024] + b  (3-term: hh + hl + lh)
// Output stored as fp16. Wt layouts transposed: [1024][K]. blockIdx.z selects.
template<int K>
__global__ __launch_bounds__(256) void k_gemm_mfma(
    const ushort_t* __restrict__ Ahi, const ushort_t* __restrict__ Alo, int M,
    const ushort_t* __restrict__ W0hi, const ushort_t* __restrict__ W0lo,
    const float* __restrict__ b0, _Float16* __restrict__ O0,
    const ushort_t* __restrict__ W1hi, const ushort_t* __restrict__ W1lo,
    const float* __restrict__ b1, _Float16* __restrict__ O1)
{
    const ushort_t* Whi = blockIdx.z ? W1hi : W0hi;
    const ushort_t* Wlo = blockIdx.z ? W1lo : W0lo;
    const float*    bi  = blockIdx.z ? b1 : b0;
    _Float16*       O   = blockIdx.z ? O1 : O0;

    const int r0 = blockIdx.x * 128;
    const int c0 = blockIdx.y * 128;

    __shared__ __align__(16) ushort_t As_hi[128 * 64];
    __shared__ __align__(16) ushort_t As_lo[128 * 64];
    __shared__ __align__(16) ushort_t Ws_hi[128 * 64];
    __shared__ __align__(16) ushort_t Ws_lo[128 * 64];

    const int t = threadIdx.x;
    const int lane = t & 63;
    const int wv = t >> 6, wr = wv >> 1, wc = wv & 1;
    const int fr = lane & 15;            // fragment row/col
    const int k0 = (lane >> 4) * 8;      // k-slice within 32

    f32x4 acc[4][4] = {};

    for (int kt = 0; kt < K; kt += 64) {
        // ---- stage (reg -> LDS, XOR-swizzled writes) ----
        #pragma unroll
        for (int p = 0; p < 4; ++p) {
            int idx = p * 256 + t;       // 0..1023
            int m  = idx >> 3;           // 0..127
            int kc = (idx & 7) * 8;      // 0..56
            int gr = r0 + m;
            uint4 vh = make_uint4(0, 0, 0, 0), vl = make_uint4(0, 0, 0, 0);
            if (gr < M) {
                vh = *(const uint4*)(Ahi + (size_t)gr * K + kt + kc);
                vl = *(const uint4*)(Alo + (size_t)gr * K + kt + kc);
            }
            int sw = (m * 128 + kc * 2) ^ ((m & 7) << 4);
            *(uint4*)((char*)As_hi + sw) = vh;
            *(uint4*)((char*)As_lo + sw) = vl;
            uint4 wh = *(const uint4*)(Whi + (size_t)(c0 + m) * K + kt + kc);
            uint4 wl = *(const uint4*)(Wlo + (size_t)(c0 + m) * K + kt + kc);
            *(uint4*)((char*)Ws_hi + sw) = wh;
            *(uint4*)((char*)Ws_lo + sw) = wl;
        }
        __syncthreads();

        // ---- MFMA ----
        #pragma unroll
        for (int ks = 0; ks < 64; ks += 32) {
            short8 ah[4], al[4], bh[4], bl[4];
            #pragma unroll
            for (int i = 0; i < 4; ++i) {
                int row = wr * 64 + i * 16 + fr;
                int off = (row * 128 + (ks + k0) * 2) ^ ((row & 7) << 4);
                ah[i] = *(const short8*)((const char*)As_hi + off);
                al[i] = *(const short8*)((const char*)As_lo + off);
            }
            #pragma unroll
            for (int j = 0; j < 4; ++j) {
                int col = wc * 64 + j * 16 + fr;
                int off = (col * 128 + (ks + k0) * 2) ^ ((col & 7) << 4);
                bh[j] = *(const short8*)((const char*)Ws_hi + off);
                bl[j] = *(const short8*)((const char*)Ws_lo + off);
            }
            #pragma unroll
            for (int i = 0; i < 4; ++i)
                #pragma unroll
                for (int j = 0; j < 4; ++j) {
                    acc[i][j] = __builtin_amdgcn_mfma_f32_16x16x32_bf16(ah[i], bh[j], acc[i][j], 0, 0, 0);
                    acc[i][j] = __builtin_amdgcn_mfma_f32_16x16x32_bf16(ah[i], bl[j], acc[i][j], 0, 0, 0);
                    acc[i][j] = __builtin_amdgcn_mfma_f32_16x16x32_bf16(al[i], bh[j], acc[i][j], 0, 0, 0);
                }
        }
        __syncthreads();
    }

    // ---- epilogue: + bias, convert to fp16, store ----
    float bj[4];
    #pragma unroll
    for (int j = 0; j < 4; ++j) bj[j] = bi[c0 + wc * 64 + j * 16 + fr];
    #pragma unroll
    for (int i = 0; i < 4; ++i) {
        int rbase = r0 + wr * 64 + i * 16 + (lane >> 4) * 4;
        #pragma unroll
        for (int r = 0; r < 4; ++r) {
            int gr = rbase + r;
            if (gr < M) {
                #pragma unroll
                for (int j = 0; j < 4; ++j)
                    O[(size_t)gr * 1024 + c0 + wc * 64 + j * 16 + fr] =
                        (_Float16)(acc[i][j][r] + bj[j]);
            }
        }
    }
}

// ------------------------------------------------- attention + aggregation
// one wave per node; lane = (head h = lane>>2, c-chunk cc = lane&3, 16 c each)
// xl/xr are fp16. SPLIT=1: write bf16 hi/lo; SPLIT=0: write fp32.
template<int SPLIT>
__global__ __launch_bounds__(256) void k_attn(
    const _Float16* __restrict__ xl, const _Float16* __restrict__ xr,
    const float* __restrict__ att, const float* __restrict__ bias,
    const int* __restrict__ rowptr, const int* __restrict__ csr,
    float* __restrict__ hout, ushort_t* __restrict__ hhi, ushort_t* __restrict__ hlo)
{
    const int wave = threadIdx.x >> 6;
    const int lane = threadIdx.x & 63;
    const int n = blockIdx.x * 4 + wave;
    if (n >= NN) return;
    const int h  = lane >> 2;
    const int cc = lane & 3;
    const int cb = h * NH + cc * 16;          // col base within [16*64]

    float attv[16], xrv[16], acc[16];
    #pragma unroll
    for (int i = 0; i < 4; ++i)
        *(float4*)(attv + i * 4) = *(const float4*)(att + cb + i * 4);
    {
        half8 q0 = *(const half8*)(xr + (size_t)n * 1024 + cb);
        half8 q1 = *(const half8*)(xr + (size_t)n * 1024 + cb + 8);
        #pragma unroll
        for (int j = 0; j < 8; ++j) { xrv[j] = (float)q0[j]; xrv[8 + j] = (float)q1[j]; }
    }
    #pragma unroll
    for (int j = 0; j < 16; ++j) acc[j] = 0.f;

    float m = -INFINITY, den = 0.f;
    const int e0 = rowptr[n], e1 = rowptr[n + 1];
    int e = e0;

    // 2-edge unrolled main loop (ILP on the gather loads)
    for (; e + 2 <= e1; e += 2) {
        const int s0 = csr[e], s1 = csr[e + 1];
        const _Float16* p0 = xl + (size_t)s0 * 1024 + cb;
        const _Float16* p1 = xl + (size_t)s1 * 1024 + cb;
        half8 a0 = *(const half8*)p0;
        half8 a1 = *(const half8*)(p0 + 8);
        half8 b0 = *(const half8*)p1;
        half8 b1 = *(const half8*)(p1 + 8);
        float x0[16], x1[16];
        #pragma unroll
        for (int j = 0; j < 8; ++j) {
            x0[j] = (float)a0[j]; x0[8 + j] = (float)a1[j];
            x1[j] = (float)b0[j]; x1[8 + j] = (float)b1[j];
        }
        float l0 = 0.f, l1 = 0.f;
        #pragma unroll
        for (int j = 0; j < 16; ++j) {
            float t0 = x0[j] + xrv[j];
            float t1 = x1[j] + xrv[j];
            t0 = fmaxf(t0, 0.2f * t0);
            t1 = fmaxf(t1, 0.2f * t1);
            l0 = fmaf(t0, attv[j], l0);
            l1 = fmaf(t1, attv[j], l1);
        }
        l0 += __shfl_xor(l0, 1); l1 += __shfl_xor(l1, 1);
        l0 += __shfl_xor(l0, 2); l1 += __shfl_xor(l1, 2);
        // sequential online-softmax updates (values already in regs)
        {
            const float nm = fmaxf(m, l0);
            const float p  = __expf(l0 - nm);
            const float sc = __expf(m - nm);
            den = den * sc + p;
            #pragma unroll
            for (int j = 0; j < 16; ++j) acc[j] = fmaf(acc[j], sc, p * x0[j]);
            m = nm;
        }
        {
            const float nm = fmaxf(m, l1);
            const float p  = __expf(l1 - nm);
            const float sc = __expf(m - nm);
            den = den * sc + p;
            #pragma unroll
            for (int j = 0; j < 16; ++j) acc[j] = fmaf(acc[j], sc, p * x1[j]);
            m = nm;
        }
    }
    // tail edge
    for (; e < e1; ++e) {
        const int s = csr[e];
        const _Float16* p0 = xl + (size_t)s * 1024 + cb;
        half8 a0 = *(const half8*)p0;
        half8 a1 = *(const half8*)(p0 + 8);
        float x0[16];
        #pragma unroll
        for (int j = 0; j < 8; ++j) { x0[j] = (float)a0[j]; x0[8 + j] = (float)a1[j]; }
        float l0 = 0.f;
        #pragma unroll
        for (int j = 0; j < 16; ++j) {
            float t0 = x0[j] + xrv[j];
            t0 = fmaxf(t0, 0.2f * t0);
            l0 = fmaf(t0, attv[j], l0);
        }
        l0 += __shfl_xor(l0, 1);
        l0 += __shfl_xor(l0, 2);
        const float nm = fmaxf(m, l0);
        const float p  = __expf(l0 - nm);
        const float sc = __expf(m - nm);
        den = den * sc + p;
        #pragma unroll
        for (int j = 0; j < 16; ++j) acc[j] = fmaf(acc[j], sc, p * x0[j]);
        m = nm;
    }

    const float inv = 1.f / den;
    float v[16];
    #pragma unroll
    for (int j = 0; j < 16; ++j) v[j] = acc[j] * inv;
    #pragma unroll
    for (int mask = 4; mask <= 32; mask <<= 1)
        #pragma unroll
        for (int j = 0; j < 16; ++j) v[j] += __shfl_xor(v[j], mask);

    if (h == 0) {                                        // lanes 0..3 hold head-sums
        float bvv[16];
        #pragma unroll
        for (int i = 0; i < 4; ++i)
            *(float4*)(bvv + i * 4) = *(const float4*)(bias + cc * 16 + i * 4);
        #pragma unroll
        for (int i = 0; i < 4; ++i) {
            float o[4];
            #pragma unroll
            for (int r = 0; r < 4; ++r) {
                float tt = v[i * 4 + r] * 0.0625f + bvv[i * 4 + r];
                o[r] = fmaxf(tt, 0.01f * tt);            // out LeakyReLU(0.01)
            }
            if (SPLIT) {
                ushort4 hh, ll;
                hh.x = f2bf_rn(o[0]); ll.x = f2bf_rn(o[0] - bf2f(hh.x));
                hh.y = f2bf_rn(o[1]); ll.y = f2bf_rn(o[1] - bf2f(hh.y));
                hh.z = f2bf_rn(o[2]); ll.z = f2bf_rn(o[2] - bf2f(hh.z));
                hh.w = f2bf_rn(o[3]); ll.w = f2bf_rn(o[3] - bf2f(hh.w));
                *(ushort4*)(hhi + (size_t)n * NH + cc * 16 + i * 4) = hh;
                *(ushort4*)(hlo + (size_t)n * NH + cc * 16 + i * 4) = ll;
            } else {
                *(float4*)(hout + (size_t)n * NH + cc * 16 + i * 4) =
                    make_float4(o[0], o[1], o[2], o[3]);
            }
        }
    }
}

// ---------------------------------------------------------------- pooling
// stage 1: 256-thread blocks over 128-node windows; lane=channel (coalesced),
// run-length accumulate over sorted batch ids, one atomicAdd per transition.
#define PNODES 128
__global__ __launch_bounds__(256) void k_pool_partial(
    const float* __restrict__ h2, const int* __restrict__ batch,
    float* __restrict__ sums)
{
    const int n0 = blockIdx.x * PNODES;
    const int c = threadIdx.x & 63;
    const int r = threadIdx.x >> 6;          // 0..3
    const int nend = (n0 + PNODES < NN) ? n0 + PNODES : NN;
    float s = 0.f;
    int bcur = -1;
    for (int n = n0 + r; n < nend; n += 4) {
        int b = batch[n];                     // wave-uniform -> broadcast
        if (b != bcur) {
            if (bcur >= 0) atomicAdd(&sums[bcur * NH + c], s);
            bcur = b; s = 0.f;
        }
        s += h2[(size_t)n * NH + c];
    }
    if (bcur >= 0) atomicAdd(&sums[bcur * NH + c], s);
}

// stage 2: divide by counts (from bstart) and apply both linear heads
__global__ void k_heads(const float* __restrict__ sums, const int* __restrict__ bstart,
                        const float* __restrict__ Wc, const float* __restrict__ bc,
                        const float* __restrict__ Wv, const float* __restrict__ bv,
                        float* __restrict__ out)
{
    const int b = blockIdx.x, c = threadIdx.x;   // 64 threads
    const float cnt = (float)(bstart[b + 1] - bstart[b]);
    const float pooled = sums[b * NH + c] / fmaxf(cnt, 1.f);
    __shared__ float pl[NH];
    pl[c] = pooled;
    __syncthreads();
    if (c < NCLS) {
        float a = bc[c];
        for (int k = 0; k < NH; ++k) a = fmaf(pl[k], Wc[k * NCLS + c], a);
        out[b * NCLS + c] = a;
    } else if (c == NCLS) {
        float a = bv[0];
        for (int k = 0; k < NH; ++k) a = fmaf(pl[k], Wv[k], a);
        out[NBAT * NCLS + b] = a;
    }
}

// ---------------------------------------------------------------- launch
extern "C" void kernel_launch(void* const* d_in, const int* in_sizes, int n_in,
                              void* d_out, int out_size, void* d_ws, size_t ws_size,
                              hipStream_t stream)
{
    const float* x     = (const float*)d_in[0];
    const int*   ei    = (const int*)  d_in[1];
    const int*   batch = (const int*)  d_in[2];
    const float* W1l = (const float*)d_in[3],  *b1l = (const float*)d_in[4];
    const float* W1r = (const float*)d_in[5],  *b1r = (const float*)d_in[6];
    const float* att1 = (const float*)d_in[7], *bias1 = (const float*)d_in[8];
    const float* W2l = (const float*)d_in[9],  *b2l = (const float*)d_in[10];
    const float* W2r = (const float*)d_in[11], *b2r = (const float*)d_in[12];
    const float* att2 = (const float*)d_in[13], *bias2 = (const float*)d_in[14];
    const float* Wc = (const float*)d_in[15],  *bc = (const float*)d_in[16];
    const float* Wv = (const float*)d_in[17],  *bv = (const float*)d_in[18];
    float* out = (float*)d_out;

    char* ws = (char*)d_ws;
    size_t off = 0;
    auto carve = [&](size_t bytes) {
        char* p = ws + off;
        off = (off + bytes + 255) & ~(size_t)255;
        return p;
    };
    _Float16* xl    = (_Float16*)carve((size_t)NN * 1024 * 2);
    _Float16* xr    = (_Float16*)carve((size_t)NN * 1024 * 2);
    float*    h2    = (float*)carve((size_t)NN * NH * 4);
    float*    psums = (float*)carve((size_t)NBAT * NH * 4);
    ushort_t* Axhi  = (ushort_t*)carve((size_t)NN * NF * 2);
    ushort_t* Axlo  = (ushort_t*)carve((size_t)NN * NF * 2);
    ushort_t* h1hi  = (ushort_t*)carve((size_t)NN * NH * 2);
    ushort_t* h1lo  = (ushort_t*)carve((size_t)NN * NH * 2);
    ushort_t* Wt1lh = (ushort_t*)carve((size_t)1024 * NF * 2);
    ushort_t* Wt1ll = (ushort_t*)carve((size_t)1024 * NF * 2);
    ushort_t* Wt1rh = (ushort_t*)carve((size_t)1024 * NF * 2);
    ushort_t* Wt1rl = (ushort_t*)carve((size_t)1024 * NF * 2);
    ushort_t* Wt2lh = (ushort_t*)carve((size_t)1024 * NH * 2);
    ushort_t* Wt2ll = (ushort_t*)carve((size_t)1024 * NH * 2);
    ushort_t* Wt2rh = (ushort_t*)carve((size_t)1024 * NH * 2);
    ushort_t* Wt2rl = (ushort_t*)carve((size_t)1024 * NH * 2);
    int*      deg    = (int*)carve((size_t)NN * 4);
    int*      cursor = (int*)carve((size_t)NN * 4);
    int*      rowptr = (int*)carve((size_t)(NN + 1) * 4);
    int*      csr    = (int*)carve((size_t)ETOT * 4);
    int*      bstart = (int*)carve((size_t)(NBAT + 1) * 4);

    // graph preprocessing
    k_init_deg<<<(NN + 255) / 256, 256, 0, stream>>>(deg);
    k_hist   <<<(EE + 255) / 256, 256, 0, stream>>>(ei, deg);
    k_scan   <<<1, 1024, 0, stream>>>(deg, rowptr, cursor);
    k_scatter<<<(ETOT + 255) / 256, 256, 0, stream>>>(ei, cursor, csr);
    k_bounds <<<(NN + 255) / 256, 256, 0, stream>>>(batch, bstart);

    // input splits
    k_split_a<<<(NN * NF / 4 + 255) / 256, 256, 0, stream>>>(x, Axhi, Axlo, NN * NF / 4);
    k_split_w<NF><<<(NF * 1024 + 255) / 256, 256, 0, stream>>>(W1l, Wt1lh, Wt1ll);
    k_split_w<NF><<<(NF * 1024 + 255) / 256, 256, 0, stream>>>(W1r, Wt1rh, Wt1rl);
    k_split_w<NH><<<(NH * 1024 + 255) / 256, 256, 0, stream>>>(W2l, Wt2lh, Wt2ll);
    k_split_w<NH><<<(NH * 1024 + 255) / 256, 256, 0, stream>>>(W2r, Wt2rh, Wt2rl);

    const int MB = (NN + 127) / 128;   // 157 row blocks
    // layer 1
    k_gemm_mfma<NF><<<dim3(MB, 8, 2), 256, 0, stream>>>(
        Axhi, Axlo, NN, Wt1lh, Wt1ll, b1l, xl, Wt1rh, Wt1rl, b1r, xr);
    k_attn<1><<<NN / 4, 256, 0, stream>>>(xl, xr, att1, bias1, rowptr, csr,
                                          (float*)nullptr, h1hi, h1lo);
    // layer 2
    k_gemm_mfma<NH><<<dim3(MB, 8, 2), 256, 0, stream>>>(
        h1hi, h1lo, NN, Wt2lh, Wt2ll, b2l, xl, Wt2rh, Wt2rl, b2r, xr);
    k_attn<0><<<NN / 4, 256, 0, stream>>>(xl, xr, att2, bias2, rowptr, csr,
                                          h2, (ushort_t*)nullptr, (ushort_t*)nullptr);
    // pool + heads (two-stage, parallel)
    hipMemsetAsync(psums, 0, (size_t)NBAT * NH * 4, stream);
    k_pool_partial<<<(NN + PNODES - 1) / PNODES, 256, 0, stream>>>(h2, batch, psums);
    k_heads<<<NBAT, NH, 0, stream>>>(psums, bstart, Wc, bc, Wv, bv, out);
}